// Round 3
// baseline (167.248 us; speedup 1.0000x reference)
//
#include <hip/hip_runtime.h>

typedef short bf16x8 __attribute__((ext_vector_type(8)));
typedef float f32x4 __attribute__((ext_vector_type(4)));

#define D 128
#define NROW 98304          // 3 groups * 64 mc * 512 rows
#define X_ELEMS ((size_t)NROW * D)          // bf16 elements in ws
#define INV_COUNT 5.9604644775390625e-08f   // 1 / (64*512*512)

__device__ __forceinline__ unsigned short f2bf(float f) {
    unsigned u = __float_as_uint(f);
    u += 0x7FFFu + ((u >> 16) & 1u);        // round-to-nearest-even
    return (unsigned short)(u >> 16);
}
__device__ __forceinline__ float bf2f(unsigned short h) {
    return __uint_as_float(((unsigned)h) << 16);
}

// 8 rows per block; 32 threads per row; each thread: float4 from eps/mu/sigma,
// 4 bf16 out (ushort4 = 8 B store), width-32 shuffle reduce for sumsq.
__global__ __launch_bounds__(256) void prep_kernel(
    const float* __restrict__ mu, const float* __restrict__ sigma,
    const float* __restrict__ epsA, const float* __restrict__ epsB,
    const float* __restrict__ epsC,
    unsigned short* __restrict__ Xb, float* __restrict__ sumsq,
    float* __restrict__ out)
{
    if (blockIdx.x == 0 && threadIdx.x == 0) out[0] = 0.f;
    int t = threadIdx.x;
    int row  = blockIdx.x * 8 + (t >> 5);   // 0..NROW-1
    int ci   = t & 31;                      // float4 index within row
    int n  = row & 511;
    int gm = row >> 9;        // g*64 + m
    int g  = gm >> 6;
    int m  = gm & 63;
    const float* eps = (g == 0) ? epsA : (g == 1) ? epsB : epsC;
    float4 e = ((const float4*)(eps + ((size_t)m * 512 + n) * D))[ci];
    float4 u = ((const float4*)(mu    + ((size_t)(g * 512 + n)) * D))[ci];
    float4 s = ((const float4*)(sigma + ((size_t)(g * 512 + n)) * D))[ci];
    unsigned short b0 = f2bf(fmaf(s.x, e.x, u.x));
    unsigned short b1 = f2bf(fmaf(s.y, e.y, u.y));
    unsigned short b2 = f2bf(fmaf(s.z, e.z, u.z));
    unsigned short b3 = f2bf(fmaf(s.w, e.w, u.w));
    float f0 = bf2f(b0), f1 = bf2f(b1), f2 = bf2f(b2), f3 = bf2f(b3);
    float ss = f0 * f0 + f1 * f1 + f2 * f2 + f3 * f3;
    uint2 packed;
    packed.x = (unsigned)b0 | ((unsigned)b1 << 16);
    packed.y = (unsigned)b2 | ((unsigned)b3 << 16);
    ((uint2*)(Xb + (size_t)row * D))[ci] = packed;
    #pragma unroll
    for (int o = 16; o > 0; o >>= 1) ss += __shfl_down(ss, o, 32);
    if (ci == 0) sumsq[row] = ss;
}

// One block = one 128x128 tile of one distance matrix for one mc sample.
// No LDS staging, no barriers: each lane loads its MFMA fragments directly
// from global (L2-resident via XCD-aware slice mapping), register dbuf over K.
__global__ __launch_bounds__(256, 3) void dist_kernel(
    const unsigned short* __restrict__ Xb, const float* __restrict__ sumsq,
    float* __restrict__ out)
{
    // XCD-aware mapping: consecutive linear block ids go to different XCDs
    // (round-robin), so put the (dist,m)-slice in bits [0:3) -> each XCD works
    // on its own slice set; concurrent working set per XCD ~1.5 MB < 4 MB L2.
    const int bx   = blockIdx.x;          // 0..3071
    const int xcd  = bx & 7;
    const int k    = bx >> 3;             // 0..383
    const int j    = k >> 4;              // 0..23
    const int tile = k & 15;
    const int s    = xcd + 8 * j;         // slice 0..191 = dist*64 + m
    const int dist = s >> 6;
    const int m    = s & 63;
    const int tn   = tile >> 2, tk = tile & 3;

    // dist 0: AC (x=A=0, y=C=2); dist 1: BA (x=B=1, y=A=0); dist 2: BC (x=B=1, y=C=2)
    const int gx = (dist == 0) ? 0 : 1;
    const int gy = (dist == 1) ? 0 : 2;

    const unsigned short* Xa = Xb + (((size_t)(gx * 64 + m)) * 512 + tn * 128) * D;
    const unsigned short* Xc = Xb + (((size_t)(gy * 64 + m)) * 512 + tk * 128) * D;
    const float* ssx = sumsq + ((size_t)(gx * 64 + m)) * 512 + tn * 128;
    const float* ssy = sumsq + ((size_t)(gy * 64 + m)) * 512 + tk * 128;

    const int t = threadIdx.x;
    const int wave = t >> 6, lane = t & 63;
    const int wr = (wave >> 1) * 64;      // wave's 64x64 quadrant of the tile
    const int wc = (wave & 1) * 64;
    const int l15 = lane & 15, quad = lane >> 4;

    // Per-lane fragment base: row = wr+l15 (+fr*16), col byte = quad*16 (+ks*64)
    const unsigned short* arow = Xa + (size_t)(wr + l15) * D + quad * 8;
    const unsigned short* brow = Xc + (size_t)(wc + l15) * D + quad * 8;

    f32x4 acc[4][4] = {};
    bf16x8 a0[4], b0[4], a1[4], b1[4];

    #pragma unroll
    for (int fr = 0; fr < 4; fr++) {
        a0[fr] = *(const bf16x8*)(arow + fr * 16 * D);
        b0[fr] = *(const bf16x8*)(brow + fr * 16 * D);
    }
    #pragma unroll
    for (int ks = 0; ks < 4; ks++) {
        if (ks < 3) {           // prefetch next K-slice while MFMAs run
            const int off = (ks + 1) * 32;
            #pragma unroll
            for (int fr = 0; fr < 4; fr++) {
                if (ks & 1) {
                    a0[fr] = *(const bf16x8*)(arow + fr * 16 * D + off);
                    b0[fr] = *(const bf16x8*)(brow + fr * 16 * D + off);
                } else {
                    a1[fr] = *(const bf16x8*)(arow + fr * 16 * D + off);
                    b1[fr] = *(const bf16x8*)(brow + fr * 16 * D + off);
                }
            }
        }
        #pragma unroll
        for (int fr = 0; fr < 4; fr++)
            #pragma unroll
            for (int fc = 0; fc < 4; fc++)
                acc[fr][fc] = __builtin_amdgcn_mfma_f32_16x16x32_bf16(
                    (ks & 1) ? a1[fr] : a0[fr],
                    (ks & 1) ? b1[fc] : b0[fc],
                    acc[fr][fc], 0, 0, 0);
    }

    // Epilogue: d2 = x2 + y2 - 2*dot; C layout: col=lane&15, row=quad*4+i
    float lsum = 0.f;
    #pragma unroll
    for (int fc = 0; fc < 4; fc++) {
        float y2 = ssy[wc + fc * 16 + l15];
        #pragma unroll
        for (int fr = 0; fr < 4; fr++) {
            #pragma unroll
            for (int i = 0; i < 4; i++) {
                float x2 = ssx[wr + fr * 16 + quad * 4 + i];
                float d2 = fmaxf(fmaf(-2.f, acc[fr][fc][i], x2 + y2), 1e-12f);
                if (dist == 0) {
                    lsum += d2;                               // mean(dAC^2)
                } else if (d2 < 4.f) {                        // relu(M - d), M=2
                    float td = 2.f - sqrtf(d2);
                    lsum += td * td;
                }
            }
        }
    }

    #pragma unroll
    for (int o = 32; o > 0; o >>= 1) lsum += __shfl_down(lsum, o, 64);
    __shared__ float red[4];
    if (lane == 0) red[wave] = lsum;
    __syncthreads();
    if (t == 0) {
        float bs = red[0] + red[1] + red[2] + red[3];
        atomicAdd(out, bs * INV_COUNT);
    }
}

extern "C" void kernel_launch(void* const* d_in, const int* in_sizes, int n_in,
                              void* d_out, int out_size, void* d_ws, size_t ws_size,
                              hipStream_t stream) {
    const float* mu    = (const float*)d_in[0];
    const float* sigma = (const float*)d_in[1];
    const float* epsA  = (const float*)d_in[2];
    const float* epsB  = (const float*)d_in[3];
    const float* epsC  = (const float*)d_in[4];
    float* out = (float*)d_out;

    unsigned short* Xb = (unsigned short*)d_ws;              // 25.17 MB bf16
    float* sumsq = (float*)((char*)d_ws + X_ELEMS * sizeof(unsigned short)); // 0.39 MB

    prep_kernel<<<NROW / 8, 256, 0, stream>>>(mu, sigma, epsA, epsB, epsC, Xb, sumsq, out);

    dist_kernel<<<3072, 256, 0, stream>>>(Xb, sumsq, out);
}

// Round 4
// 140.722 us; speedup vs baseline: 1.1885x; 1.1885x over previous
//
#include <hip/hip_runtime.h>

typedef short bf16x8 __attribute__((ext_vector_type(8)));
typedef float f32x4 __attribute__((ext_vector_type(4)));

#define D 128
#define NROW 98304          // 3 groups * 64 mc * 512 rows
#define X_ELEMS ((size_t)NROW * D)          // bf16 elements in ws
#define INV_COUNT 5.9604644775390625e-08f   // 1 / (64*512*512)

typedef __attribute__((address_space(3))) void  as3_void;
typedef const __attribute__((address_space(1))) void as1_cvoid;

__device__ __forceinline__ void gl2lds16(const void* g, void* l) {
    __builtin_amdgcn_global_load_lds((as1_cvoid*)g, (as3_void*)l, 16, 0, 0);
}
__device__ __forceinline__ void gl2lds4(const void* g, void* l) {
    __builtin_amdgcn_global_load_lds((as1_cvoid*)g, (as3_void*)l, 4, 0, 0);
}

__device__ __forceinline__ unsigned short f2bf(float f) {
    unsigned u = __float_as_uint(f);
    u += 0x7FFFu + ((u >> 16) & 1u);        // round-to-nearest-even
    return (unsigned short)(u >> 16);
}
__device__ __forceinline__ float bf2f(unsigned short h) {
    return __uint_as_float(((unsigned)h) << 16);
}

// 8 rows per block; 32 threads per row: float4 loads, 8B bf16 store,
// width-32 shuffle reduce for sum(x_bf16^2). Also zeroes the out accumulator.
__global__ __launch_bounds__(256) void prep_kernel(
    const float* __restrict__ mu, const float* __restrict__ sigma,
    const float* __restrict__ epsA, const float* __restrict__ epsB,
    const float* __restrict__ epsC,
    unsigned short* __restrict__ Xb, float* __restrict__ sumsq,
    float* __restrict__ out)
{
    if (blockIdx.x == 0 && threadIdx.x == 0) out[0] = 0.f;
    int t = threadIdx.x;
    int row  = blockIdx.x * 8 + (t >> 5);   // 0..NROW-1
    int ci   = t & 31;                      // float4 index within row
    int n  = row & 511;
    int gm = row >> 9;        // g*64 + m
    int g  = gm >> 6;
    int m  = gm & 63;
    const float* eps = (g == 0) ? epsA : (g == 1) ? epsB : epsC;
    float4 e = ((const float4*)(eps + ((size_t)m * 512 + n) * D))[ci];
    float4 u = ((const float4*)(mu    + ((size_t)(g * 512 + n)) * D))[ci];
    float4 s = ((const float4*)(sigma + ((size_t)(g * 512 + n)) * D))[ci];
    unsigned short b0 = f2bf(fmaf(s.x, e.x, u.x));
    unsigned short b1 = f2bf(fmaf(s.y, e.y, u.y));
    unsigned short b2 = f2bf(fmaf(s.z, e.z, u.z));
    unsigned short b3 = f2bf(fmaf(s.w, e.w, u.w));
    float f0 = bf2f(b0), f1 = bf2f(b1), f2 = bf2f(b2), f3 = bf2f(b3);
    float ss = f0 * f0 + f1 * f1 + f2 * f2 + f3 * f3;
    uint2 packed;
    packed.x = (unsigned)b0 | ((unsigned)b1 << 16);
    packed.y = (unsigned)b2 | ((unsigned)b3 << 16);
    ((uint2*)(Xb + (size_t)row * D))[ci] = packed;
    #pragma unroll
    for (int o = 16; o > 0; o >>= 1) ss += __shfl_down(ss, o, 32);
    if (ci == 0) sumsq[row] = ss;
}

// One block = one 128x128 tile of one distance matrix for one mc sample.
// XCD-swizzled block mapping keeps the slice L2-resident; staging is
// global_load_lds width=16 (async DMA, coalesced), fragments via ds_read_b128
// with the XOR swizzle folded into the GLOBAL gather address.
__global__ __launch_bounds__(256, 2) void dist_kernel(
    const unsigned short* __restrict__ Xb, const float* __restrict__ sumsq,
    float* __restrict__ out)
{
    const int bx   = blockIdx.x;          // 0..3071
    const int xcd  = bx & 7;
    const int k    = bx >> 3;             // 0..383
    const int j    = k >> 4;              // 0..23
    const int tile = k & 15;
    const int s    = xcd + 8 * j;         // slice 0..191 = dist*64 + m
    const int dist = s >> 6;
    const int m    = s & 63;
    const int tn   = tile >> 2, tk = tile & 3;

    // dist 0: AC (x=A=0, y=C=2); dist 1: BA (x=B=1, y=A=0); dist 2: BC (x=B=1, y=C=2)
    const int gx = (dist == 0) ? 0 : 1;
    const int gy = (dist == 1) ? 0 : 2;

    const char* Xa = (const char*)(Xb + (((size_t)(gx * 64 + m)) * 512 + tn * 128) * D);
    const char* Xc = (const char*)(Xb + (((size_t)(gy * 64 + m)) * 512 + tk * 128) * D);
    const float* ssx = sumsq + ((size_t)(gx * 64 + m)) * 512 + tn * 128;
    const float* ssy = sumsq + ((size_t)(gy * 64 + m)) * 512 + tk * 128;

    __shared__ unsigned short lds[2 * 128 * 128];   // 64 KB
    __shared__ float ss_s[256];                     // x2 rows | y2 rows
    unsigned short* As = lds;
    unsigned short* Bs = lds + 128 * 128;

    const int t = threadIdx.x;
    const int wave = t >> 6, lane = t & 63;
    const int wr = (wave >> 1) * 64;      // wave's 64x64 quadrant
    const int wc = (wave & 1) * 64;
    const int l15 = lane & 15, quad = lane >> 4;

    // ---- staging: LDS granule c = row*16 + (g ^ (row&7)); lane covers LDS
    // granules in order, so the XOR goes into the global gather address.
    {
        const int dr = lane >> 4;          // row within the 4-row instr span
        const int sg = lane & 15;          // LDS granule within row
        const int voffE = dr * 256 + ((sg ^ dr) * 16);        // r0%8 == 0
        const int voffO = dr * 256 + ((sg ^ (dr + 4)) * 16);  // r0%8 == 4
        #pragma unroll
        for (int i = 0; i < 8; i++) {
            const int r0 = wave * 32 + i * 4;
            const int voff = (i & 1) ? voffO : voffE;
            gl2lds16(Xa + r0 * 256 + voff, &As[r0 * 128]);
            gl2lds16(Xc + r0 * 256 + voff, &Bs[r0 * 128]);
        }
        const float* sp = (wave & 2) ? ssy : ssx;
        gl2lds4(sp + (wave & 1) * 64 + lane, &ss_s[wave * 64]);
    }
    __syncthreads();

    // ---- MFMA main: K=128 in 4 steps of 32 ----
    f32x4 acc[4][4] = {};
    #pragma unroll
    for (int ks = 0; ks < 4; ks++) {
        const int gsw = ((ks * 4 + quad) ^ (l15 & 7)) * 8;   // swizzled granule, shorts
        bf16x8 a[4], b[4];
        #pragma unroll
        for (int fr = 0; fr < 4; fr++)
            a[fr] = *(bf16x8*)&As[(wr + fr * 16 + l15) * 128 + gsw];
        #pragma unroll
        for (int fc = 0; fc < 4; fc++)
            b[fc] = *(bf16x8*)&Bs[(wc + fc * 16 + l15) * 128 + gsw];
        #pragma unroll
        for (int fr = 0; fr < 4; fr++)
            #pragma unroll
            for (int fc = 0; fc < 4; fc++)
                acc[fr][fc] = __builtin_amdgcn_mfma_f32_16x16x32_bf16(
                    a[fr], b[fc], acc[fr][fc], 0, 0, 0);
    }

    // ---- epilogue: d2 = x2 + y2 - 2*dot; C layout: col=lane&15, row=quad*4+i
    float lsum = 0.f;
    #pragma unroll
    for (int fc = 0; fc < 4; fc++) {
        float y2 = ss_s[128 + wc + fc * 16 + l15];
        #pragma unroll
        for (int fr = 0; fr < 4; fr++) {
            #pragma unroll
            for (int i = 0; i < 4; i++) {
                float x2 = ss_s[wr + fr * 16 + quad * 4 + i];
                float d2 = fmaxf(fmaf(-2.f, acc[fr][fc][i], x2 + y2), 1e-12f);
                if (dist == 0) {
                    lsum += d2;                               // mean(dAC^2)
                } else if (d2 < 4.f) {                        // relu(M - d), M=2
                    float td = 2.f - sqrtf(d2);
                    lsum += td * td;
                }
            }
        }
    }

    #pragma unroll
    for (int o = 32; o > 0; o >>= 1) lsum += __shfl_down(lsum, o, 64);
    __syncthreads();                      // ss_s reads done; safe to reuse
    float* red = ss_s;
    if (lane == 0) red[wave] = lsum;
    __syncthreads();
    if (t == 0) {
        float bs = red[0] + red[1] + red[2] + red[3];
        atomicAdd(out, bs * INV_COUNT);
    }
}

extern "C" void kernel_launch(void* const* d_in, const int* in_sizes, int n_in,
                              void* d_out, int out_size, void* d_ws, size_t ws_size,
                              hipStream_t stream) {
    const float* mu    = (const float*)d_in[0];
    const float* sigma = (const float*)d_in[1];
    const float* epsA  = (const float*)d_in[2];
    const float* epsB  = (const float*)d_in[3];
    const float* epsC  = (const float*)d_in[4];
    float* out = (float*)d_out;

    unsigned short* Xb = (unsigned short*)d_ws;              // 25.17 MB bf16
    float* sumsq = (float*)((char*)d_ws + X_ELEMS * sizeof(unsigned short)); // 0.39 MB

    prep_kernel<<<NROW / 8, 256, 0, stream>>>(mu, sigma, epsA, epsB, epsC, Xb, sumsq, out);

    dist_kernel<<<3072, 256, 0, stream>>>(Xb, sumsq, out);
}

// Round 5
// 132.187 us; speedup vs baseline: 1.2652x; 1.0646x over previous
//
#include <hip/hip_runtime.h>

typedef short bf16x8 __attribute__((ext_vector_type(8)));
typedef float f32x4 __attribute__((ext_vector_type(4)));

#define D 128
#define NROW 98304          // 3 groups * 64 mc * 512 rows
#define X_ELEMS ((size_t)NROW * D)          // bf16 elements in ws
#define INV_COUNT 5.9604644775390625e-08f   // 1 / (64*512*512)

typedef __attribute__((address_space(3))) void  as3_void;
typedef const __attribute__((address_space(1))) void as1_cvoid;

__device__ __forceinline__ void gl2lds16(const void* g, void* l) {
    __builtin_amdgcn_global_load_lds((as1_cvoid*)g, (as3_void*)l, 16, 0, 0);
}
__device__ __forceinline__ void gl2lds4(const void* g, void* l) {
    __builtin_amdgcn_global_load_lds((as1_cvoid*)g, (as3_void*)l, 4, 0, 0);
}

__device__ __forceinline__ unsigned short f2bf(float f) {
    unsigned u = __float_as_uint(f);
    u += 0x7FFFu + ((u >> 16) & 1u);        // round-to-nearest-even
    return (unsigned short)(u >> 16);
}
__device__ __forceinline__ float bf2f(unsigned short h) {
    return __uint_as_float(((unsigned)h) << 16);
}

// 8 rows per block; 32 threads per row: float4 loads, 8B bf16 store,
// width-32 shuffle reduce for sum(x_bf16^2). Also zeroes the out accumulator.
__global__ __launch_bounds__(256) void prep_kernel(
    const float* __restrict__ mu, const float* __restrict__ sigma,
    const float* __restrict__ epsA, const float* __restrict__ epsB,
    const float* __restrict__ epsC,
    unsigned short* __restrict__ Xb, float* __restrict__ sumsq,
    float* __restrict__ out)
{
    if (blockIdx.x == 0 && threadIdx.x == 0) out[0] = 0.f;
    int t = threadIdx.x;
    int row  = blockIdx.x * 8 + (t >> 5);   // 0..NROW-1
    int ci   = t & 31;                      // float4 index within row
    int n  = row & 511;
    int gm = row >> 9;        // g*64 + m
    int g  = gm >> 6;
    int m  = gm & 63;
    const float* eps = (g == 0) ? epsA : (g == 1) ? epsB : epsC;
    float4 e = ((const float4*)(eps + ((size_t)m * 512 + n) * D))[ci];
    float4 u = ((const float4*)(mu    + ((size_t)(g * 512 + n)) * D))[ci];
    float4 s = ((const float4*)(sigma + ((size_t)(g * 512 + n)) * D))[ci];
    unsigned short b0 = f2bf(fmaf(s.x, e.x, u.x));
    unsigned short b1 = f2bf(fmaf(s.y, e.y, u.y));
    unsigned short b2 = f2bf(fmaf(s.z, e.z, u.z));
    unsigned short b3 = f2bf(fmaf(s.w, e.w, u.w));
    float f0 = bf2f(b0), f1 = bf2f(b1), f2 = bf2f(b2), f3 = bf2f(b3);
    float ss = f0 * f0 + f1 * f1 + f2 * f2 + f3 * f3;
    uint2 packed;
    packed.x = (unsigned)b0 | ((unsigned)b1 << 16);
    packed.y = (unsigned)b2 | ((unsigned)b3 << 16);
    ((uint2*)(Xb + (size_t)row * D))[ci] = packed;
    #pragma unroll
    for (int o = 16; o > 0; o >>= 1) ss += __shfl_down(ss, o, 32);
    if (ci == 0) sumsq[row] = ss;
}

// Strip-persistent pipelined dist: block = (slice, tn) computes a 128x512
// strip (4 tiles, tk=0..3) sharing one As (staged once). Bs double-buffers
// half-K (16 KB) pieces: the DMA for phase p+1 is issued BEFORE phase p's
// ds_read+MFMA, so the compiler's forced vmcnt(0)-before-barrier is hidden
// behind ~500+ cycles of compute instead of draining cold.
__global__ __launch_bounds__(256, 2) void dist_kernel(
    const unsigned short* __restrict__ Xb, const float* __restrict__ sumsq,
    float* __restrict__ out)
{
    const int bx  = blockIdx.x;           // 0..767
    const int xcd = bx & 7;               // XCD round-robin -> slice locality
    const int q   = bx >> 3;              // 0..95
    const int j   = q >> 2;               // 0..23
    const int tn  = q & 3;
    const int s   = xcd + 8 * j;          // slice 0..191 = dist*64 + m
    const int dist = s >> 6;
    const int m    = s & 63;

    // dist 0: AC (x=A=0, y=C=2); dist 1: BA (x=B=1, y=A=0); dist 2: BC (x=B=1, y=C=2)
    const int gx = (dist == 0) ? 0 : 1;
    const int gy = (dist == 1) ? 0 : 2;

    const char* Xa = (const char*)(Xb + (((size_t)(gx * 64 + m)) * 512 + tn * 128) * D);
    const char* Xc = (const char*)(Xb + (((size_t)(gy * 64 + m)) * 512) * D);  // full slice
    const float* ssx = sumsq + ((size_t)(gx * 64 + m)) * 512 + tn * 128;
    const float* ssy = sumsq + ((size_t)(gy * 64 + m)) * 512;

    __shared__ unsigned short As[128 * 128];     // 32 KB, K-full A strip
    __shared__ unsigned short Bs[2][128 * 64];   // 2 x 16 KB half-K pieces
    __shared__ float ss_s[644];                  // [0:128) x2 | [128:640) y2 (all tk)

    const int t = threadIdx.x;
    const int wave = t >> 6, lane = t & 63;
    const int wr = (wave >> 1) * 64, wc = (wave & 1) * 64;
    const int l15 = lane & 15, quad = lane >> 4;

    const int dr4 = lane >> 4, g16 = lane & 15;  // As staging: 4 rows/instr
    const int dr8 = lane >> 3, g8  = lane & 7;   // Bs staging: 8 rows/instr

    // ---- fill: As (whole strip), Bs[0] (tile0 half0), sumsq rows ----
    #pragma unroll
    for (int i = 0; i < 8; i++) {
        const int r0 = wave * 32 + i * 4;
        const int row = r0 + dr4;
        gl2lds16(Xa + row * 256 + ((g16 ^ (row & 7)) * 16), &As[r0 * 128]);
    }
    #pragma unroll
    for (int i = 0; i < 4; i++) {
        const int r0 = wave * 8 + i * 32;
        const int row = r0 + dr8;
        gl2lds16(Xc + row * 256 + ((g8 ^ (row & 7)) * 16), &Bs[0][r0 * 64]);
    }
    #pragma unroll
    for (int i = 0; i < 3; i++) {
        const int idx = wave + i * 4;
        if (idx < 10) {
            const float* src = (idx < 2) ? (ssx + idx * 64) : (ssy + idx * 64 - 128);
            gl2lds4(src + lane, &ss_s[idx * 64]);
        }
    }
    __syncthreads();

    float lsum = 0.f;
    f32x4 acc[4][4] = {};

    #pragma unroll
    for (int p = 0; p < 8; p++) {                // phase = (tile tk = p>>1, kh = p&1)
        const int buf = p & 1;
        if (p < 7) {                             // prefetch next phase's Bs piece
            const int tk2 = (p + 1) >> 1, kh2 = (p + 1) & 1;
            #pragma unroll
            for (int i = 0; i < 4; i++) {
                const int r0 = wave * 8 + i * 32;
                const int row = r0 + dr8;
                gl2lds16(Xc + (tk2 * 128 + row) * 256 + kh2 * 128 +
                             ((g8 ^ (row & 7)) * 16),
                         &Bs[buf ^ 1][r0 * 64]);
            }
        }
        const int kh = p & 1;
        #pragma unroll
        for (int ki = 0; ki < 2; ki++) {
            const int pa = ((kh * 2 + ki) * 4 + quad) ^ (l15 & 7);   // As granule pos
            const int pb = (ki * 4 + quad) ^ (l15 & 7);              // Bs granule pos
            bf16x8 a[4], b[4];
            #pragma unroll
            for (int fr = 0; fr < 4; fr++)
                a[fr] = *(bf16x8*)&As[(wr + fr * 16 + l15) * 128 + pa * 8];
            #pragma unroll
            for (int fc = 0; fc < 4; fc++)
                b[fc] = *(bf16x8*)&Bs[buf][(wc + fc * 16 + l15) * 64 + pb * 8];
            #pragma unroll
            for (int fr = 0; fr < 4; fr++)
                #pragma unroll
                for (int fc = 0; fc < 4; fc++)
                    acc[fr][fc] = __builtin_amdgcn_mfma_f32_16x16x32_bf16(
                        a[fr], b[fc], acc[fr][fc], 0, 0, 0);
        }
        if (kh) {   // tile tk complete: epilogue, reset acc
            const int tk = p >> 1;
            #pragma unroll
            for (int fc = 0; fc < 4; fc++) {
                float y2 = ss_s[128 + tk * 128 + wc + fc * 16 + l15];
                #pragma unroll
                for (int fr = 0; fr < 4; fr++) {
                    #pragma unroll
                    for (int i = 0; i < 4; i++) {
                        float x2 = ss_s[wr + fr * 16 + quad * 4 + i];
                        float d2 = fmaxf(fmaf(-2.f, acc[fr][fc][i], x2 + y2), 1e-12f);
                        if (dist == 0) {
                            lsum += d2;                       // mean(dAC^2)
                        } else if (d2 < 4.f) {                // relu(M - d), M=2
                            float td = 2.f - sqrtf(d2);
                            lsum += td * td;
                        }
                        acc[fr][fc][i] = 0.f;
                    }
                }
            }
        }
        __syncthreads();
    }

    #pragma unroll
    for (int o = 32; o > 0; o >>= 1) lsum += __shfl_down(lsum, o, 64);
    if (lane == 0) ss_s[wave] = lsum;     // x2 region dead after last epilogue
    __syncthreads();
    if (t == 0) {
        atomicAdd(out, (ss_s[0] + ss_s[1] + ss_s[2] + ss_s[3]) * INV_COUNT);
    }
}

extern "C" void kernel_launch(void* const* d_in, const int* in_sizes, int n_in,
                              void* d_out, int out_size, void* d_ws, size_t ws_size,
                              hipStream_t stream) {
    const float* mu    = (const float*)d_in[0];
    const float* sigma = (const float*)d_in[1];
    const float* epsA  = (const float*)d_in[2];
    const float* epsB  = (const float*)d_in[3];
    const float* epsC  = (const float*)d_in[4];
    float* out = (float*)d_out;

    unsigned short* Xb = (unsigned short*)d_ws;              // 25.17 MB bf16
    float* sumsq = (float*)((char*)d_ws + X_ELEMS * sizeof(unsigned short)); // 0.39 MB

    prep_kernel<<<NROW / 8, 256, 0, stream>>>(mu, sigma, epsA, epsB, epsC, Xb, sumsq, out);

    dist_kernel<<<768, 256, 0, stream>>>(Xb, sumsq, out);
}